// Round 1
// 317.529 us; speedup vs baseline: 1.1291x; 1.1291x over previous
//
#include <hip/hip_runtime.h>
#include <math.h>

#define L_SEQ 2048
#define B_SZ 16
#define DIN 64
#define H_SZ 512
#define N_ST 64
#define N_LAYERS 4
#define Q_CHUNK 64
#define N_CHUNKS (L_SEQ / Q_CHUNK)   // 32

typedef _Float16 f16;
typedef _Float16 f16x8 __attribute__((ext_vector_type(8)));
typedef _Float16 f16x4 __attribute__((ext_vector_type(4)));
typedef _Float16 f16x2 __attribute__((ext_vector_type(2)));
typedef float    f32x4 __attribute__((ext_vector_type(4)));
typedef float    f32x2 __attribute__((ext_vector_type(2)));

// ---------- cross-lane helpers ----------
template <int CTRL>
__device__ __forceinline__ float dpp_add(float x) {
    int s = __builtin_amdgcn_update_dpp(0, __builtin_bit_cast(int, x), CTRL, 0xF, 0xF, false);
    return x + __builtin_bit_cast(float, s);
}
// 64-lane sum, valid in lane 63 (all on VALU pipe)
__device__ __forceinline__ float wave_sum_lane63(float x) {
    x = dpp_add<0x111>(x);
    x = dpp_add<0x112>(x);
    x = dpp_add<0x114>(x);
    x = dpp_add<0x118>(x);
    x = dpp_add<0x142>(x);
    x = dpp_add<0x143>(x);
    return x;
}

// Barrier that drains ONLY lgkmcnt (LDS) — leaves global loads/stores in
// flight across the barrier (T3/T4: the u-prefetch is consumed a full chunk
// later, the y-store has no intra-kernel reader). Single asm block so the
// scheduler cannot place anything between the wait and the barrier; "memory"
// clobber orders all LDS traffic around it.
__device__ __forceinline__ void barrier_lgkm() {
    asm volatile("s_waitcnt lgkmcnt(0)\n\ts_barrier" ::: "memory");
}

// ---------- encoder (MFMA): out[h][b][l] = sum_k x[l][b][k] W[k][h] + bias[h] ----------
__global__ __launch_bounds__(256, 4)
void encoder_mfma_kernel(const float* __restrict__ x, const float* __restrict__ W,
                         const float* __restrict__ bias, float* __restrict__ out)
{
    __shared__ f16   x_sh[64][72];    // [l][k]   9216 B
    __shared__ f16   w_t[64][72];     // [h][k]   9216 B
    __shared__ float out_sh[64][68];  //          17408 B
    __shared__ float b_sh[64];
    const int tid = threadIdx.x;
    const int bid = blockIdx.x;
    const int bb  = bid & 15;
    const int lt  = (bid >> 4) & 31;
    const int ht  = bid >> 9;
    const int l0 = lt * 64, h0 = ht * 64;

#pragma unroll
    for (int i = 0; i < 16; ++i) {
        int idx = tid + i * 256;
        int r = idx >> 6, c = idx & 63;
        x_sh[r][c] = (f16)x[((size_t)(l0 + r) * B_SZ + bb) * DIN + c];  // r=l, c=k
        w_t[c][r]  = (f16)W[(size_t)r * H_SZ + h0 + c];                 // r=k, c=h
    }
    if (tid < 64) b_sh[tid] = bias[h0 + tid];
    __syncthreads();

    const int wave = tid >> 6;
    const int lane = tid & 63;
    const int frow = lane & 15;
    const int fk   = (lane >> 4) * 8;
    const int m0   = wave * 16;            // h strip per wave

    f16x8 a0 = *(const f16x8*)&w_t[m0 + frow][fk];
    f16x8 a1 = *(const f16x8*)&w_t[m0 + frow][fk + 32];
    float bv[4];
#pragma unroll
    for (int j = 0; j < 4; ++j) bv[j] = b_sh[m0 + (lane >> 4) * 4 + j];

#pragma unroll
    for (int nt = 0; nt < 4; ++nt) {       // l tiles
        f16x8 b0 = *(const f16x8*)&x_sh[nt * 16 + frow][fk];
        f16x8 b1 = *(const f16x8*)&x_sh[nt * 16 + frow][fk + 32];
        f32x4 acc = {0.f, 0.f, 0.f, 0.f};
        acc = __builtin_amdgcn_mfma_f32_16x16x32_f16(a0, b0, acc, 0, 0, 0);
        acc = __builtin_amdgcn_mfma_f32_16x16x32_f16(a1, b1, acc, 0, 0, 0);
        // D: col = lane&15 (= l within tile), row = (lane>>4)*4+j (= h within strip)
#pragma unroll
        for (int j = 0; j < 4; ++j)
            out_sh[m0 + (lane >> 4) * 4 + j][nt * 16 + frow] = acc[j] + bv[j];
    }
    __syncthreads();

#pragma unroll
    for (int i = 0; i < 4; ++i) {
        int row = (tid >> 4) + i * 16;     // h row
        int c4  = (tid & 15) * 4;          // l col
        f32x4 v = *(const f32x4*)&out_sh[row][c4];
        float4 o; o.x = v[0]; o.y = v[1]; o.z = v[2]; o.w = v[3];
        *(float4*)&out[((size_t)(h0 + row) * B_SZ + bb) * L_SEQ + l0 + c4] = o;
    }
}

// ---------- S4D layer: chunked conv + state correction, one block per h ----------
// Layouts (all conflict-free for the b128 access pattern):
//   A_lds rows 0..63  : Toeplitz(K)[t][t']          (M = t)
//   A_lds rows 64..191: E interleaved [2n+p][m]     (M = n2, p=0 Re / p=1 Im)
//   G_lds [t][n2]     : n2 = 2n (+2Re(C dA^{t+1})), 2n+1 (-2Im)
//   U_sh  [buf][b][t] f16 ; s_frag [buf][b][n2] f16 (interleaved)
//   z_sh  [b][n2] f32 ; yp_sh [b][t] f32
// State (fp32) lives in registers: thread (b=wave, n=lane).
__global__ __launch_bounds__(1024, 8)
void s4d_layer_kernel(const float* __restrict__ u_in,   // [H][B][L]
                      float* __restrict__ y_out,        // [H][B][L]
                      const float* __restrict__ log_dt, const float* __restrict__ log_A_re,
                      const float* __restrict__ A_im, const float* __restrict__ C_re,
                      const float* __restrict__ C_im, const float* __restrict__ Dskip,
                      float* __restrict__ st_re, float* __restrict__ st_im, int layer)
{
    __shared__ f16   A_lds[192][72];      // 27648 B
    __shared__ f16   G_lds[64][136];      // 17408 B
    __shared__ f16   U_sh[2][16][72];     //  4608 B
    __shared__ f16   s_frag[2][16][136];  //  8704 B
    __shared__ float z_sh[16][136];       //  8704 B
    __shared__ float yp_sh[16][72];       //  4608 B
    __shared__ float K_sh[64];            //   256 B   -> 71936 B total, 2 blocks/CU

    const int tid  = threadIdx.x;
    const int wave = tid >> 6;
    const int lane = tid & 63;
    const int h    = blockIdx.x;

    const int ph = layer * H_SZ + h;
    const int pn = ph * N_ST + lane;

    float wr, wi;                          // dA^64 for n = lane (every thread)
    // ---- per-h table build (all waves run the power recurrence for n=lane) ----
    {
        float dt   = expf(log_dt[ph]);
        float Are  = -expf(log_A_re[pn]);
        float Aim  = A_im[pn];
        float mg   = expf(dt * Are);
        float phs  = dt * Aim;
        float dAr  = mg * cosf(phs);
        float dAi  = mg * sinf(phs);
        float invd = 1.0f / (Are * Are + Aim * Aim);
        float nr   = dAr - 1.0f;
        float dBr  = (nr * Are + dAi * Aim) * invd;
        float dBi  = (dAi * Are - nr * Aim) * invd;
        float Cr   = C_re[pn];
        float Ci   = C_im[pn];
        float CBr  = Cr * dBr - Ci * dBi;
        float CBi  = Cr * dBi + Ci * dBr;

        float Pr = 1.f, Pi = 0.f;          // P = dA^j
        for (int j = 0; j <= 64; ++j) {
            if (j <= 63) {
                if (wave == 2) {
                    float ks = wave_sum_lane63(2.f * (Pr * CBr - Pi * CBi));
                    if (lane == 63) K_sh[j] = ks;
                }
                if (wave == 0) {           // E rows interleaved: [2n]=Re, [2n+1]=Im
                    A_lds[64 + 2 * lane][63 - j]     = (f16)(Pr * dBr - Pi * dBi);
                    A_lds[64 + 2 * lane + 1][63 - j] = (f16)(Pr * dBi + Pi * dBr);
                }
            }
            if (j >= 1 && wave == 1) {     // G[t=j-1][n2]
                G_lds[j - 1][2 * lane]     = (f16)( 2.f * (Cr * Pr - Ci * Pi));
                G_lds[j - 1][2 * lane + 1] = (f16)(-2.f * (Cr * Pi + Ci * Pr));
            }
            if (j == 64) { wr = Pr; wi = Pi; }
            float nPr = Pr * dAr - Pi * dAi;
            float nPi = Pr * dAi + Pi * dAr;
            Pr = nPr; Pi = nPi;
        }
    }
    __syncthreads();
    // Toeplitz expansion + s_frag zero-init
#pragma unroll
    for (int e = tid; e < 64 * 64; e += 1024) {
        int i = e >> 6, j = e & 63;
        A_lds[i][j] = (j <= i) ? (f16)K_sh[i - j] : (f16)0.f;
    }
    for (int e = tid; e < 2 * 16 * 136 / 2; e += 1024)
        ((unsigned int*)s_frag)[e] = 0u;
    __syncthreads();

    // ---- preload chunk-invariant MFMA A-fragments into registers ----
    const int frow = lane & 15;
    const int fk   = (lane >> 4) * 8;
    f16x8 a_frag[4];
    if (wave < 12) {
        const int m0 = wave * 16;
#pragma unroll
        for (int ks = 0; ks < 2; ++ks)
            a_frag[ks] = *(const f16x8*)&A_lds[m0 + frow][fk + 32 * ks];
    } else {
        const int m0 = (wave - 12) * 16;
#pragma unroll
        for (int ks = 0; ks < 4; ++ks)
            a_frag[ks] = *(const f16x8*)&G_lds[m0 + frow][fk + 32 * ks];
    }

    const float Dv = Dskip[ph];
    const float* ub = u_in + (size_t)h * B_SZ * L_SEQ;
    float*       yb = y_out + (size_t)h * B_SZ * L_SEQ;

    float sr = 0.f, si = 0.f;              // state regs: (b=wave, n=lane)
    float v = ub[(size_t)wave * L_SEQ + lane];   // prefetched u chunk 0

    for (int c = 0; c < N_CHUNKS; ++c) {
        const int buf = c & 1;
        // stage current chunk (wave=b), issue prefetch for next chunk
        U_sh[buf][wave][lane] = (f16)v;    // compiler inserts vmcnt wait for v HERE
        float vn = 0.f;
        if (c + 1 < N_CHUNKS)
            vn = ub[(size_t)wave * L_SEQ + (c + 1) * 64 + lane];
        barrier_lgkm();                    // U_sh[buf], s_frag[buf] visible; vn stays in flight

        f32x4 acc = {0.f, 0.f, 0.f, 0.f};
        if (wave < 12) {                   // [T;E](192x64) . U(64x16)
#pragma unroll
            for (int ks = 0; ks < 2; ++ks) {
                f16x8 bv = *(const f16x8*)&U_sh[buf][frow][fk + 32 * ks];
                acc = __builtin_amdgcn_mfma_f32_16x16x32_f16(a_frag[ks], bv, acc, 0, 0, 0);
            }
        } else {                           // G(64x128) . S(128x16)
#pragma unroll
            for (int ks = 0; ks < 4; ++ks) {
                f16x8 bv = *(const f16x8*)&s_frag[buf][frow][fk + 32 * ks];
                acc = __builtin_amdgcn_mfma_f32_16x16x32_f16(a_frag[ks], bv, acc, 0, 0, 0);
            }
        }
        if (wave >= 4 && wave < 12) {      // z rows n2 (4 consecutive) at col b=frow
            *(f32x4*)&z_sh[frow][(wave * 16 - 64) + (lane >> 4) * 4] = acc;
        } else if (wave >= 12) {           // yp rows t at col b=frow
            *(f32x4*)&yp_sh[frow][(wave - 12) * 16 + (lane >> 4) * 4] = acc;
        }
        barrier_lgkm();                    // z, yp visible; y-store of prev chunk stays in flight

        if (wave < 4) {                    // y = conv + corr + D*u -> global
            const int t0c = wave * 16 + (lane >> 4) * 4;
            f32x4 yp = *(const f32x4*)&yp_sh[frow][t0c];
            f16x4 uf = *(const f16x4*)&U_sh[buf][frow][t0c];
            float4 yv;
            yv.x = acc[0] + yp[0] + Dv * (float)uf[0];
            yv.y = acc[1] + yp[1] + Dv * (float)uf[1];
            yv.z = acc[2] + yp[2] + Dv * (float)uf[2];
            yv.w = acc[3] + yp[3] + Dv * (float)uf[3];
            *(float4*)&yb[(size_t)frow * L_SEQ + c * 64 + t0c] = yv;
        }
        {                                  // state update: s = w*s + z
            f32x2 z = *(const f32x2*)&z_sh[wave][2 * lane];
            float nre = wr * sr - wi * si + z[0];
            float nim = wi * sr + wr * si + z[1];
            sr = nre; si = nim;
            f16x2 sf; sf[0] = (f16)nre; sf[1] = (f16)nim;
            *(f16x2*)&s_frag[buf ^ 1][wave][2 * lane] = sf;
        }
        v = vn;
    }

    // final states -> [NL,B,H,N] straight from registers (coalesced over n)
    {
        const size_t so = (((size_t)layer * B_SZ + wave) * H_SZ + h) * N_ST + lane;
        st_re[so] = sr;
        st_im[so] = si;
    }
}

// ---------- [H][B][L] -> [L][B][H] transpose ----------
__global__ __launch_bounds__(256, 4)
void hbl_to_lbh_kernel(const float* __restrict__ in, float* __restrict__ out)
{
    __shared__ float t_sh[64][65];
    const int tid = threadIdx.x, bid = blockIdx.x;
    const int bb = bid & 15, lt = (bid >> 4) & 31, ht = bid >> 9;
    const int l0 = lt * 64, h0 = ht * 64;
#pragma unroll
    for (int i = 0; i < 16; ++i) {
        int idx = tid + i * 256;
        int hh = idx >> 6, ll = idx & 63;
        t_sh[hh][ll] = in[((size_t)(h0 + hh) * B_SZ + bb) * L_SEQ + l0 + ll];
    }
    __syncthreads();
#pragma unroll
    for (int i = 0; i < 16; ++i) {
        int idx = tid + i * 256;
        int ll = idx >> 6, hh = idx & 63;
        out[((size_t)(l0 + ll) * B_SZ + bb) * H_SZ + h0 + hh] = t_sh[hh][ll];
    }
}

extern "C" void kernel_launch(void* const* d_in, const int* in_sizes, int n_in,
                              void* d_out, int out_size, void* d_ws, size_t ws_size,
                              hipStream_t stream)
{
    const float* x        = (const float*)d_in[0];
    const float* enc_W    = (const float*)d_in[1];
    const float* enc_b    = (const float*)d_in[2];
    const float* log_dt   = (const float*)d_in[3];
    const float* log_A_re = (const float*)d_in[4];
    const float* A_im     = (const float*)d_in[5];
    const float* C_re     = (const float*)d_in[6];
    const float* C_im     = (const float*)d_in[7];
    const float* Dskip    = (const float*)d_in[8];

    float* out_lbh = (float*)d_out;                                  // [L,B,H]
    float* st_re   = out_lbh + (size_t)L_SEQ * B_SZ * H_SZ;
    float* st_im   = st_re + (size_t)N_LAYERS * B_SZ * H_SZ * N_ST;
    float* B0 = (float*)d_ws;        // [H][B][L] scratch (64 MB)
    float* B1 = out_lbh;             // reuse d_out y-region as [H][B][L] scratch

    encoder_mfma_kernel<<<4096, 256, 0, stream>>>(x, enc_W, enc_b, B0);

    s4d_layer_kernel<<<512, 1024, 0, stream>>>(B0, B1, log_dt, log_A_re, A_im,
                                               C_re, C_im, Dskip, st_re, st_im, 0);
    s4d_layer_kernel<<<512, 1024, 0, stream>>>(B1, B0, log_dt, log_A_re, A_im,
                                               C_re, C_im, Dskip, st_re, st_im, 1);
    s4d_layer_kernel<<<512, 1024, 0, stream>>>(B0, B1, log_dt, log_A_re, A_im,
                                               C_re, C_im, Dskip, st_re, st_im, 2);
    s4d_layer_kernel<<<512, 1024, 0, stream>>>(B1, B0, log_dt, log_A_re, A_im,
                                               C_re, C_im, Dskip, st_re, st_im, 3);

    hbl_to_lbh_kernel<<<4096, 256, 0, stream>>>(B0, out_lbh);        // final y -> [L,B,H]
}

// Round 2
// 298.941 us; speedup vs baseline: 1.1993x; 1.0622x over previous
//
#include <hip/hip_runtime.h>
#include <math.h>

#define L_SEQ 2048
#define B_SZ 16
#define DIN 64
#define H_SZ 512
#define N_ST 64
#define N_LAYERS 4
#define Q_CHUNK 64
#define N_CHUNKS (L_SEQ / Q_CHUNK)   // 32
#define UPAD 2056                     // U_all row stride in f16 (2048 + 8): 16B-aligned, 2-way-free banks

typedef _Float16 f16;
typedef _Float16 f16x8 __attribute__((ext_vector_type(8)));
typedef _Float16 f16x4 __attribute__((ext_vector_type(4)));
typedef _Float16 f16x2 __attribute__((ext_vector_type(2)));
typedef float    f32x4 __attribute__((ext_vector_type(4)));
typedef float    f32x2 __attribute__((ext_vector_type(2)));

// ---------- cross-lane helpers ----------
template <int CTRL>
__device__ __forceinline__ float dpp_add(float x) {
    int s = __builtin_amdgcn_update_dpp(0, __builtin_bit_cast(int, x), CTRL, 0xF, 0xF, false);
    return x + __builtin_bit_cast(float, s);
}
__device__ __forceinline__ float wave_sum_lane63(float x) {
    x = dpp_add<0x111>(x);
    x = dpp_add<0x112>(x);
    x = dpp_add<0x114>(x);
    x = dpp_add<0x118>(x);
    x = dpp_add<0x142>(x);
    x = dpp_add<0x143>(x);
    return x;
}

// LDS-only barrier (global loads/stores may stay in flight across it)
__device__ __forceinline__ void barrier_lgkm() {
    asm volatile("s_waitcnt lgkmcnt(0)\n\ts_barrier" ::: "memory");
}

// ---------- encoder (MFMA): out[h][b][l] = sum_k x[l][b][k] W[k][h] + bias[h] ----------
__global__ __launch_bounds__(256, 4)
void encoder_mfma_kernel(const float* __restrict__ x, const float* __restrict__ W,
                         const float* __restrict__ bias, float* __restrict__ out)
{
    __shared__ f16   x_sh[64][72];    // [l][k]
    __shared__ f16   w_t[64][72];     // [h][k]
    __shared__ float out_sh[64][68];
    __shared__ float b_sh[64];
    const int tid = threadIdx.x;
    const int bid = blockIdx.x;
    const int bb  = bid & 15;
    const int lt  = (bid >> 4) & 31;
    const int ht  = bid >> 9;
    const int l0 = lt * 64, h0 = ht * 64;

#pragma unroll
    for (int i = 0; i < 16; ++i) {
        int idx = tid + i * 256;
        int r = idx >> 6, c = idx & 63;
        x_sh[r][c] = (f16)x[((size_t)(l0 + r) * B_SZ + bb) * DIN + c];  // r=l, c=k
        w_t[c][r]  = (f16)W[(size_t)r * H_SZ + h0 + c];                 // r=k, c=h
    }
    if (tid < 64) b_sh[tid] = bias[h0 + tid];
    __syncthreads();

    const int wave = tid >> 6;
    const int lane = tid & 63;
    const int frow = lane & 15;
    const int fk   = (lane >> 4) * 8;
    const int m0   = wave * 16;            // h strip per wave

    f16x8 a0 = *(const f16x8*)&w_t[m0 + frow][fk];
    f16x8 a1 = *(const f16x8*)&w_t[m0 + frow][fk + 32];
    float bv[4];
#pragma unroll
    for (int j = 0; j < 4; ++j) bv[j] = b_sh[m0 + (lane >> 4) * 4 + j];

#pragma unroll
    for (int nt = 0; nt < 4; ++nt) {       // l tiles
        f16x8 b0 = *(const f16x8*)&x_sh[nt * 16 + frow][fk];
        f16x8 b1 = *(const f16x8*)&x_sh[nt * 16 + frow][fk + 32];
        f32x4 acc = {0.f, 0.f, 0.f, 0.f};
        acc = __builtin_amdgcn_mfma_f32_16x16x32_f16(a0, b0, acc, 0, 0, 0);
        acc = __builtin_amdgcn_mfma_f32_16x16x32_f16(a1, b1, acc, 0, 0, 0);
#pragma unroll
        for (int j = 0; j < 4; ++j)
            out_sh[m0 + (lane >> 4) * 4 + j][nt * 16 + frow] = acc[j] + bv[j];
    }
    __syncthreads();

#pragma unroll
    for (int i = 0; i < 4; ++i) {
        int row = (tid >> 4) + i * 16;     // h row
        int c4  = (tid & 15) * 4;          // l col
        f32x4 v = *(const f32x4*)&out_sh[row][c4];
        float4 o; o.x = v[0]; o.y = v[1]; o.z = v[2]; o.w = v[3];
        *(float4*)&out[((size_t)(h0 + row) * B_SZ + bb) * L_SEQ + l0 + c4] = o;
    }
}

// ---------- fused 4-layer S4D: one block per h, sequence LDS-resident ----------
// Wave roles per chunk-iteration c (single barrier per iter; all handoffs
// double-buffered with a 1-iteration lag):
//   waves 4-11 ("Z"):    write S_pre(chunk c) -> s_frag[c&1]; Z_c = E.U_c (2 MFMA);
//                        register scan s = dA^64 * s + Z_c (2 complex pairs/thread)
//   waves 12-15 ("conv"): yp_c = T.U_c + D*u  -> yp_sh[c&1]  (2 MFMA)
//   waves 0-3  ("out"):  chunk c-1: G.S (4 MFMA) + yp_sh[(c-1)&1] -> y
//                        (layers 0-2: y written back in place to U_all as f16;
//                         layer 3: float4 store to global)
// The only inter-chunk serial dependence is the Z-waves' register scan.
__global__ __launch_bounds__(1024, 4)
void s4d_fused_kernel(float* __restrict__ u_io,        // [H][B][L] f32: encoder out; final y in-place
                      const float* __restrict__ log_dt, const float* __restrict__ log_A_re,
                      const float* __restrict__ A_im, const float* __restrict__ C_re,
                      const float* __restrict__ C_im, const float* __restrict__ Dskip,
                      float* __restrict__ st_re, float* __restrict__ st_im)
{
    __shared__ f16   A_lds[192][72];      // rows 0-63: Toeplitz(K)[t][t'], rows 64-191: E[2n+p][t]
    __shared__ f16   G_lds[64][136];      // G[t][n2]
    __shared__ f16   U_all[16][UPAD];     // whole per-h sequence, f16, in-place across layers
    __shared__ f16   s_frag[2][16][136];  // S_pre per chunk [b][n2]
    __shared__ float yp_sh[2][16][76];    // conv + D*u per chunk [b][t] (stride 76: 2-way-free)
    __shared__ float K_sh[64];
    __shared__ float w_sh[64][2];         // dA^64 per n
    // total: 27648+17408+65792+8704+9728+256+512 = 130048 B -> 1 block/CU

    const int tid  = threadIdx.x;
    const int wave = tid >> 6;
    const int lane = tid & 63;
    const int h    = blockIdx.x;
    const int frow = lane & 15;
    const int fq   = lane >> 4;
    const int fk   = fq * 8;

    // ---- stage the whole layer-0 input sequence into LDS as f16 ----
    {
        const float* ub = u_io + ((size_t)h * B_SZ + wave) * L_SEQ;
#pragma unroll
        for (int p = 0; p < 8; ++p) {
            float4 v4 = *(const float4*)&ub[(p * 64 + lane) * 4];
            f16x4 o; o[0] = (f16)v4.x; o[1] = (f16)v4.y; o[2] = (f16)v4.z; o[3] = (f16)v4.w;
            *(f16x4*)&U_all[wave][(p * 64 + lane) * 4] = o;
        }
    }
    float* yb = u_io + (size_t)h * B_SZ * L_SEQ;   // final-layer output (safe: input fully in LDS)

    for (int layer = 0; layer < N_LAYERS; ++layer) {
        const int ph = layer * H_SZ + h;
        const int pn = ph * N_ST + lane;

        // ---- per-(layer,h) table build (waves 0:E, 1:G, 2:K, 3:w_sh) ----
        float wr = 1.f, wi = 0.f;
        {
            float dt   = expf(log_dt[ph]);
            float Are  = -expf(log_A_re[pn]);
            float Aim  = A_im[pn];
            float mg   = expf(dt * Are);
            float phs  = dt * Aim;
            float dAr  = mg * cosf(phs);
            float dAi  = mg * sinf(phs);
            float invd = 1.0f / (Are * Are + Aim * Aim);
            float nr   = dAr - 1.0f;
            float dBr  = (nr * Are + dAi * Aim) * invd;
            float dBi  = (dAi * Are - nr * Aim) * invd;
            float Cr   = C_re[pn];
            float Ci   = C_im[pn];
            float CBr  = Cr * dBr - Ci * dBi;
            float CBi  = Cr * dBi + Ci * dBr;

            float Pr = 1.f, Pi = 0.f;          // P = dA^j
            for (int j = 0; j <= 64; ++j) {
                if (j <= 63) {
                    if (wave == 2) {
                        float ks = wave_sum_lane63(2.f * (Pr * CBr - Pi * CBi));
                        if (lane == 63) K_sh[j] = ks;
                    }
                    if (wave == 0) {
                        A_lds[64 + 2 * lane][63 - j]     = (f16)(Pr * dBr - Pi * dBi);
                        A_lds[64 + 2 * lane + 1][63 - j] = (f16)(Pr * dBi + Pi * dBr);
                    }
                }
                if (j >= 1 && wave == 1) {
                    G_lds[j - 1][2 * lane]     = (f16)( 2.f * (Cr * Pr - Ci * Pi));
                    G_lds[j - 1][2 * lane + 1] = (f16)(-2.f * (Cr * Pi + Ci * Pr));
                }
                if (j == 64) { wr = Pr; wi = Pi; }
                float nPr = Pr * dAr - Pi * dAi;
                float nPi = Pr * dAi + Pi * dAr;
                Pr = nPr; Pi = nPi;
            }
        }
        if (wave == 3) { w_sh[lane][0] = wr; w_sh[lane][1] = wi; }
        __syncthreads();
#pragma unroll
        for (int e = tid; e < 64 * 64; e += 1024) {   // Toeplitz expansion
            int i = e >> 6, j = e & 63;
            A_lds[i][j] = (j <= i) ? (f16)K_sh[i - j] : (f16)0.f;
        }
        __syncthreads();

        // ---- per-role chunk-invariant fragments / constants ----
        const float Dv = Dskip[ph];
        f16x8 a_frag[4];
        float s0r = 0.f, s0i = 0.f, s1r = 0.f, s1i = 0.f;   // Z-wave state (2 complex pairs)
        float war = 0.f, wai = 0.f, wbr = 0.f, wbi = 0.f;    // dA^64 for those pairs
        if (wave >= 4 && wave < 12) {           // E rows: A_lds rows 16*wave (64..176)
            const int m0 = wave * 16;
            a_frag[0] = *(const f16x8*)&A_lds[m0 + frow][fk];
            a_frag[1] = *(const f16x8*)&A_lds[m0 + frow][fk + 32];
            const int na = (wave - 4) * 8 + fq * 2;
            war = w_sh[na][0];     wai = w_sh[na][1];
            wbr = w_sh[na + 1][0]; wbi = w_sh[na + 1][1];
        } else if (wave >= 12) {                // Toeplitz rows 0..63
            const int m0 = (wave - 12) * 16;
            a_frag[0] = *(const f16x8*)&A_lds[m0 + frow][fk];
            a_frag[1] = *(const f16x8*)&A_lds[m0 + frow][fk + 32];
        } else {                                // G rows 0..63
            const int m0 = wave * 16;
#pragma unroll
            for (int ks = 0; ks < 4; ++ks)
                a_frag[ks] = *(const f16x8*)&G_lds[m0 + frow][fk + 32 * ks];
        }

        // ---- main pipelined chunk loop: ONE barrier per chunk ----
#pragma unroll 2
        for (int c = 0; c < N_CHUNKS; ++c) {
            const int cb = c & 1, pb = cb ^ 1;
            if (wave >= 4 && wave < 12) {
                // publish S_pre (state before chunk c) for the correction at iter c+1
                f16x4 sf; sf[0] = (f16)s0r; sf[1] = (f16)s0i; sf[2] = (f16)s1r; sf[3] = (f16)s1i;
                *(f16x4*)&s_frag[cb][frow][(wave - 4) * 16 + fq * 4] = sf;
                f16x8 b0 = *(const f16x8*)&U_all[frow][c * 64 + fk];
                f16x8 b1 = *(const f16x8*)&U_all[frow][c * 64 + fk + 32];
                f32x4 acc = {0.f, 0.f, 0.f, 0.f};
                acc = __builtin_amdgcn_mfma_f32_16x16x32_f16(a_frag[0], b0, acc, 0, 0, 0);
                acc = __builtin_amdgcn_mfma_f32_16x16x32_f16(a_frag[1], b1, acc, 0, 0, 0);
                float t0r = war * s0r - wai * s0i + acc[0];
                float t0i = wai * s0r + war * s0i + acc[1];
                float t1r = wbr * s1r - wbi * s1i + acc[2];
                float t1i = wbi * s1r + wbr * s1i + acc[3];
                s0r = t0r; s0i = t0i; s1r = t1r; s1i = t1i;
            } else if (wave >= 12) {
                f16x8 b0 = *(const f16x8*)&U_all[frow][c * 64 + fk];
                f16x8 b1 = *(const f16x8*)&U_all[frow][c * 64 + fk + 32];
                f32x4 acc = {0.f, 0.f, 0.f, 0.f};
                acc = __builtin_amdgcn_mfma_f32_16x16x32_f16(a_frag[0], b0, acc, 0, 0, 0);
                acc = __builtin_amdgcn_mfma_f32_16x16x32_f16(a_frag[1], b1, acc, 0, 0, 0);
                const int t0 = (wave - 12) * 16 + fq * 4;
                f16x4 uf = *(const f16x4*)&U_all[frow][c * 64 + t0];
                f32x4 yo;
#pragma unroll
                for (int j = 0; j < 4; ++j) yo[j] = acc[j] + Dv * (float)uf[j];
                *(f32x4*)&yp_sh[cb][frow][t0] = yo;
            } else if (c > 0) {                 // output waves: finalize chunk c-1
                f32x4 acc = {0.f, 0.f, 0.f, 0.f};
#pragma unroll
                for (int ks = 0; ks < 4; ++ks) {
                    f16x8 bv = *(const f16x8*)&s_frag[pb][frow][fk + 32 * ks];
                    acc = __builtin_amdgcn_mfma_f32_16x16x32_f16(a_frag[ks], bv, acc, 0, 0, 0);
                }
                const int t0 = wave * 16 + fq * 4;
                f32x4 yp = *(const f32x4*)&yp_sh[pb][frow][t0];
                if (layer == N_LAYERS - 1) {
                    float4 yv;
                    yv.x = acc[0] + yp[0]; yv.y = acc[1] + yp[1];
                    yv.z = acc[2] + yp[2]; yv.w = acc[3] + yp[3];
                    *(float4*)&yb[(size_t)frow * L_SEQ + (c - 1) * 64 + t0] = yv;
                } else {
                    f16x4 o;
#pragma unroll
                    for (int j = 0; j < 4; ++j) o[j] = (f16)(acc[j] + yp[j]);
                    *(f16x4*)&U_all[frow][(c - 1) * 64 + t0] = o;
                }
            }
            barrier_lgkm();
        }

        // ---- epilogue: output for chunk 31 (buffers [31&1 = 1]) ----
        if (wave < 4) {
            f32x4 acc = {0.f, 0.f, 0.f, 0.f};
#pragma unroll
            for (int ks = 0; ks < 4; ++ks) {
                f16x8 bv = *(const f16x8*)&s_frag[1][frow][fk + 32 * ks];
                acc = __builtin_amdgcn_mfma_f32_16x16x32_f16(a_frag[ks], bv, acc, 0, 0, 0);
            }
            const int t0 = wave * 16 + fq * 4;
            f32x4 yp = *(const f32x4*)&yp_sh[1][frow][t0];
            if (layer == N_LAYERS - 1) {
                float4 yv;
                yv.x = acc[0] + yp[0]; yv.y = acc[1] + yp[1];
                yv.z = acc[2] + yp[2]; yv.w = acc[3] + yp[3];
                *(float4*)&yb[(size_t)frow * L_SEQ + 31 * 64 + t0] = yv;
            } else {
                f16x4 o;
#pragma unroll
                for (int j = 0; j < 4; ++j) o[j] = (f16)(acc[j] + yp[j]);
                *(f16x4*)&U_all[frow][31 * 64 + t0] = o;
            }
        }
        if (wave >= 4 && wave < 12) {           // final states from scan registers
            const int na = (wave - 4) * 8 + fq * 2;
            const size_t base = (((size_t)layer * B_SZ + frow) * H_SZ + h) * N_ST + na;
            st_re[base]     = s0r; st_im[base]     = s0i;
            st_re[base + 1] = s1r; st_im[base + 1] = s1i;
        }
        __syncthreads();   // tables/U_all safe to overwrite for next layer
    }
}

// ---------- [H][B][L] -> [L][B][H] transpose ----------
__global__ __launch_bounds__(256, 4)
void hbl_to_lbh_kernel(const float* __restrict__ in, float* __restrict__ out)
{
    __shared__ float t_sh[64][65];
    const int tid = threadIdx.x, bid = blockIdx.x;
    const int bb = bid & 15, lt = (bid >> 4) & 31, ht = bid >> 9;
    const int l0 = lt * 64, h0 = ht * 64;
#pragma unroll
    for (int i = 0; i < 16; ++i) {
        int idx = tid + i * 256;
        int hh = idx >> 6, ll = idx & 63;
        t_sh[hh][ll] = in[((size_t)(h0 + hh) * B_SZ + bb) * L_SEQ + l0 + ll];
    }
    __syncthreads();
#pragma unroll
    for (int i = 0; i < 16; ++i) {
        int idx = tid + i * 256;
        int ll = idx >> 6, hh = idx & 63;
        out[((size_t)(l0 + ll) * B_SZ + bb) * H_SZ + h0 + hh] = t_sh[hh][ll];
    }
}

extern "C" void kernel_launch(void* const* d_in, const int* in_sizes, int n_in,
                              void* d_out, int out_size, void* d_ws, size_t ws_size,
                              hipStream_t stream)
{
    const float* x        = (const float*)d_in[0];
    const float* enc_W    = (const float*)d_in[1];
    const float* enc_b    = (const float*)d_in[2];
    const float* log_dt   = (const float*)d_in[3];
    const float* log_A_re = (const float*)d_in[4];
    const float* A_im     = (const float*)d_in[5];
    const float* C_re     = (const float*)d_in[6];
    const float* C_im     = (const float*)d_in[7];
    const float* Dskip    = (const float*)d_in[8];

    float* out_lbh = (float*)d_out;                                  // [L,B,H]
    float* st_re   = out_lbh + (size_t)L_SEQ * B_SZ * H_SZ;
    float* st_im   = st_re + (size_t)N_LAYERS * B_SZ * H_SZ * N_ST;
    float* B0 = (float*)d_ws;        // [H][B][L] scratch (64 MB)

    encoder_mfma_kernel<<<4096, 256, 0, stream>>>(x, enc_W, enc_b, B0);

    s4d_fused_kernel<<<512, 1024, 0, stream>>>(B0, log_dt, log_A_re, A_im,
                                               C_re, C_im, Dskip, st_re, st_im);

    hbl_to_lbh_kernel<<<4096, 256, 0, stream>>>(B0, out_lbh);        // final y -> [L,B,H]
}

// Round 3
// 263.250 us; speedup vs baseline: 1.3619x; 1.1356x over previous
//
#include <hip/hip_runtime.h>
#include <math.h>

#define L_SEQ 2048
#define B_SZ 16
#define DIN 64
#define H_SZ 512
#define N_ST 64
#define N_LAYERS 4
#define Q_CHUNK 64
#define N_CHUNKS (L_SEQ / Q_CHUNK)   // 32
#define GSZ 4                         // chunks per pipeline group
#define N_GROUPS (N_CHUNKS / GSZ)     // 8
#define UPAD 2056                     // U_all row stride in f16 (16B-aligned)

typedef _Float16 f16;
typedef _Float16 f16x8 __attribute__((ext_vector_type(8)));
typedef _Float16 f16x4 __attribute__((ext_vector_type(4)));
typedef _Float16 f16x2 __attribute__((ext_vector_type(2)));
typedef float    f32x4 __attribute__((ext_vector_type(4)));
typedef float    f32x2 __attribute__((ext_vector_type(2)));

// ---------- cross-lane helpers ----------
template <int CTRL>
__device__ __forceinline__ float dpp_add(float x) {
    int s = __builtin_amdgcn_update_dpp(0, __builtin_bit_cast(int, x), CTRL, 0xF, 0xF, false);
    return x + __builtin_bit_cast(float, s);
}
__device__ __forceinline__ float wave_sum_lane63(float x) {
    x = dpp_add<0x111>(x);
    x = dpp_add<0x112>(x);
    x = dpp_add<0x114>(x);
    x = dpp_add<0x118>(x);
    x = dpp_add<0x142>(x);
    x = dpp_add<0x143>(x);
    return x;
}

// LDS-only barrier (global loads/stores may stay in flight across it)
__device__ __forceinline__ void barrier_lgkm() {
    asm volatile("s_waitcnt lgkmcnt(0)\n\ts_barrier" ::: "memory");
}

// ---------- encoder (MFMA): out[h][b][l] = f16( sum_k x[l][b][k] W[k][h] + bias[h] ) ----------
__global__ __launch_bounds__(256, 4)
void encoder_mfma_kernel(const float* __restrict__ x, const float* __restrict__ W,
                         const float* __restrict__ bias, f16* __restrict__ out)
{
    __shared__ f16   x_sh[64][72];    // [l][k]
    __shared__ f16   w_t[64][72];     // [h][k]
    __shared__ float out_sh[64][68];
    __shared__ float b_sh[64];
    const int tid = threadIdx.x;
    const int bid = blockIdx.x;
    const int bb  = bid & 15;
    const int lt  = (bid >> 4) & 31;
    const int ht  = bid >> 9;
    const int l0 = lt * 64, h0 = ht * 64;

#pragma unroll
    for (int i = 0; i < 16; ++i) {
        int idx = tid + i * 256;
        int r = idx >> 6, c = idx & 63;
        x_sh[r][c] = (f16)x[((size_t)(l0 + r) * B_SZ + bb) * DIN + c];  // r=l, c=k
        w_t[c][r]  = (f16)W[(size_t)r * H_SZ + h0 + c];                 // r=k, c=h
    }
    if (tid < 64) b_sh[tid] = bias[h0 + tid];
    __syncthreads();

    const int wave = tid >> 6;
    const int lane = tid & 63;
    const int frow = lane & 15;
    const int fk   = (lane >> 4) * 8;
    const int m0   = wave * 16;            // h strip per wave

    f16x8 a0 = *(const f16x8*)&w_t[m0 + frow][fk];
    f16x8 a1 = *(const f16x8*)&w_t[m0 + frow][fk + 32];
    float bv[4];
#pragma unroll
    for (int j = 0; j < 4; ++j) bv[j] = b_sh[m0 + (lane >> 4) * 4 + j];

#pragma unroll
    for (int nt = 0; nt < 4; ++nt) {       // l tiles
        f16x8 b0 = *(const f16x8*)&x_sh[nt * 16 + frow][fk];
        f16x8 b1 = *(const f16x8*)&x_sh[nt * 16 + frow][fk + 32];
        f32x4 acc = {0.f, 0.f, 0.f, 0.f};
        acc = __builtin_amdgcn_mfma_f32_16x16x32_f16(a0, b0, acc, 0, 0, 0);
        acc = __builtin_amdgcn_mfma_f32_16x16x32_f16(a1, b1, acc, 0, 0, 0);
#pragma unroll
        for (int j = 0; j < 4; ++j)
            out_sh[m0 + (lane >> 4) * 4 + j][nt * 16 + frow] = acc[j] + bv[j];
    }
    __syncthreads();

#pragma unroll
    for (int i = 0; i < 4; ++i) {
        int row = (tid >> 4) + i * 16;     // h row
        int c4  = (tid & 15) * 4;          // l col
        f32x4 v = *(const f32x4*)&out_sh[row][c4];
        f16x4 o;
#pragma unroll
        for (int k = 0; k < 4; ++k) o[k] = (f16)v[k];
        *(f16x4*)&out[((size_t)(h0 + row) * B_SZ + bb) * L_SEQ + l0 + c4] = o;
    }
}

// ---------- fused 4-layer S4D: one block per h, sequence LDS-resident ----------
// Group-pipelined (GSZ=4 chunks per barrier). Wave roles:
//   waves 0-7  ("scan"): per chunk j of group g: publish S_pre -> S_buf[g&1][j];
//                        Z = E.U (2 MFMA); register scan s = dA^64*s + Z.
//   waves 8-15 ("out"):  group g-1: y = T.U + G.S_buf[(g-1)&1] + D*u  (6 MFMA/chunk).
//                        Each out-wave owns (row-tile orow, chunk-pair ocp).
//                        Layers 0-2: y held in regs, written back in place to U_all
//                        at iter g+1 (group lag 2 => no read/write race).
//                        Layer 3: y stored straight to global as f16.
// ONE barrier per group-iteration (10 per layer) instead of one per chunk (32).
__global__ __launch_bounds__(1024, 4)
void s4d_fused_kernel(f16* __restrict__ u_io,          // [H][B][L] f16: encoder out; final y in place
                      const float* __restrict__ log_dt, const float* __restrict__ log_A_re,
                      const float* __restrict__ A_im, const float* __restrict__ C_re,
                      const float* __restrict__ C_im, const float* __restrict__ Dskip,
                      float* __restrict__ st_re, float* __restrict__ st_im)
{
    __shared__ f16   A_lds[192][72];         // rows 0-63: Toeplitz(K)[t][t'], 64-191: E[2n+p][t]
    __shared__ f16   G_lds[64][136];         // G[t][n2]
    __shared__ f16   U_all[16][UPAD];        // whole per-h sequence, f16, in place across layers
    __shared__ f16   S_buf[2][GSZ][16][136]; // S_pre per chunk of group [b][n2]
    __shared__ float K_sh[64];
    __shared__ float w_sh[64][2];            // dA^64 per n
    // total: 27648+17408+65792+34816+256+512 = 146432 B -> 1 block/CU

    const int tid  = threadIdx.x;
    const int wave = tid >> 6;
    const int lane = tid & 63;
    const int h    = blockIdx.x;
    const int frow = lane & 15;
    const int fq   = lane >> 4;
    const int fk   = fq * 8;

    const bool zrole = (wave < 8);
    const int  ow    = wave - 8;       // out-wave id 0..7
    const int  orow  = ow & 3;         // output row-tile (t rows 16*orow..)
    const int  ocp   = ow >> 2;        // chunk pair within group: {2*ocp, 2*ocp+1}

    // ---- stage the whole layer-0 input sequence into LDS ----
    {
        const f16* ub = u_io + ((size_t)h * B_SZ + wave) * L_SEQ;
#pragma unroll
        for (int p = 0; p < 4; ++p) {
            f16x8 v = *(const f16x8*)&ub[p * 512 + lane * 8];
            *(f16x8*)&U_all[wave][p * 512 + lane * 8] = v;
        }
    }
    f16* yb = u_io + (size_t)h * B_SZ * L_SEQ;   // final-layer f16 output (same h slot, safe)

    for (int layer = 0; layer < N_LAYERS; ++layer) {
        const int ph = layer * H_SZ + h;
        const int pn = ph * N_ST + lane;

        // ---- per-(layer,h) table build (waves 0:E, 1:G, 2:K, 3:w_sh) ----
        float wr = 1.f, wi = 0.f;
        {
            float dt   = expf(log_dt[ph]);
            float Are  = -expf(log_A_re[pn]);
            float Aim  = A_im[pn];
            float mg   = expf(dt * Are);
            float phs  = dt * Aim;
            float dAr  = mg * cosf(phs);
            float dAi  = mg * sinf(phs);
            float invd = 1.0f / (Are * Are + Aim * Aim);
            float nr   = dAr - 1.0f;
            float dBr  = (nr * Are + dAi * Aim) * invd;
            float dBi  = (dAi * Are - nr * Aim) * invd;
            float Cr   = C_re[pn];
            float Ci   = C_im[pn];
            float CBr  = Cr * dBr - Ci * dBi;
            float CBi  = Cr * dBi + Ci * dBr;

            float Pr = 1.f, Pi = 0.f;          // P = dA^j
            for (int j = 0; j <= 64; ++j) {
                if (j <= 63) {
                    if (wave == 2) {
                        float ks = wave_sum_lane63(2.f * (Pr * CBr - Pi * CBi));
                        if (lane == 63) K_sh[j] = ks;
                    }
                    if (wave == 0) {
                        A_lds[64 + 2 * lane][63 - j]     = (f16)(Pr * dBr - Pi * dBi);
                        A_lds[64 + 2 * lane + 1][63 - j] = (f16)(Pr * dBi + Pi * dBr);
                    }
                }
                if (j >= 1 && wave == 1) {
                    G_lds[j - 1][2 * lane]     = (f16)( 2.f * (Cr * Pr - Ci * Pi));
                    G_lds[j - 1][2 * lane + 1] = (f16)(-2.f * (Cr * Pi + Ci * Pr));
                }
                if (j == 64) { wr = Pr; wi = Pi; }
                float nPr = Pr * dAr - Pi * dAi;
                float nPi = Pr * dAi + Pi * dAr;
                Pr = nPr; Pi = nPi;
            }
        }
        if (wave == 3) { w_sh[lane][0] = wr; w_sh[lane][1] = wi; }
        __syncthreads();
#pragma unroll
        for (int e = tid; e < 64 * 64; e += 1024) {   // Toeplitz expansion
            int i = e >> 6, j = e & 63;
            A_lds[i][j] = (j <= i) ? (f16)K_sh[i - j] : (f16)0.f;
        }
        __syncthreads();

        // ---- per-role chunk-invariant fragments / constants ----
        const float Dv = Dskip[ph];
        f16x8 aE[2], aT[2], aG[4];
        float s0r = 0.f, s0i = 0.f, s1r = 0.f, s1i = 0.f;   // scan state (2 complex pairs)
        float war = 0.f, wai = 0.f, wbr = 0.f, wbi = 0.f;
        if (zrole) {
            const int m0 = 64 + wave * 16;          // E row-tile
            aE[0] = *(const f16x8*)&A_lds[m0 + frow][fk];
            aE[1] = *(const f16x8*)&A_lds[m0 + frow][fk + 32];
            const int na = wave * 8 + fq * 2;
            war = w_sh[na][0];     wai = w_sh[na][1];
            wbr = w_sh[na + 1][0]; wbi = w_sh[na + 1][1];
        } else {
            const int m0 = orow * 16;
            aT[0] = *(const f16x8*)&A_lds[m0 + frow][fk];
            aT[1] = *(const f16x8*)&A_lds[m0 + frow][fk + 32];
#pragma unroll
            for (int ks = 0; ks < 4; ++ks)
                aG[ks] = *(const f16x8*)&G_lds[m0 + frow][fk + 32 * ks];
        }
        f32x4 yh0 = {0.f,0.f,0.f,0.f}, yh1 = {0.f,0.f,0.f,0.f};   // held y (layers 0-2)

        // ---- main pipelined group loop: ONE barrier per group-iteration ----
#pragma unroll 2
        for (int g = 0; g <= N_GROUPS + 1; ++g) {
            if (zrole) {
                if (g < N_GROUPS) {
                    const int gb = g & 1;
#pragma unroll
                    for (int j = 0; j < GSZ; ++j) {
                        f16x4 sf; sf[0] = (f16)s0r; sf[1] = (f16)s0i;
                        sf[2] = (f16)s1r; sf[3] = (f16)s1i;
                        *(f16x4*)&S_buf[gb][j][frow][wave * 16 + fq * 4] = sf;
                        const int co = (g * GSZ + j) * 64;
                        f16x8 b0 = *(const f16x8*)&U_all[frow][co + fk];
                        f16x8 b1 = *(const f16x8*)&U_all[frow][co + fk + 32];
                        f32x4 acc = {0.f, 0.f, 0.f, 0.f};
                        acc = __builtin_amdgcn_mfma_f32_16x16x32_f16(aE[0], b0, acc, 0, 0, 0);
                        acc = __builtin_amdgcn_mfma_f32_16x16x32_f16(aE[1], b1, acc, 0, 0, 0);
                        float t0r = war * s0r - wai * s0i + acc[0];
                        float t0i = wai * s0r + war * s0i + acc[1];
                        float t1r = wbr * s1r - wbi * s1i + acc[2];
                        float t1i = wbi * s1r + wbr * s1i + acc[3];
                        s0r = t0r; s0i = t0i; s1r = t1r; s1i = t1i;
                    }
                }
            } else {
                const int t0 = orow * 16 + fq * 4;
                if (layer < N_LAYERS - 1 && g >= 2) {   // write held y (group g-2) in place
                    const int c0 = ((g - 2) * GSZ + ocp * 2) * 64;
                    f16x4 o0, o1;
#pragma unroll
                    for (int k = 0; k < 4; ++k) { o0[k] = (f16)yh0[k]; o1[k] = (f16)yh1[k]; }
                    *(f16x4*)&U_all[frow][c0 + t0]      = o0;
                    *(f16x4*)&U_all[frow][c0 + 64 + t0] = o1;
                }
                if (g >= 1 && g <= N_GROUPS) {          // compute group g-1
                    const int gp = g - 1;
                    const int pb = gp & 1;
#pragma unroll
                    for (int jj = 0; jj < 2; ++jj) {
                        const int j  = ocp * 2 + jj;
                        const int co = (gp * GSZ + j) * 64;
                        f32x4 acc = {0.f, 0.f, 0.f, 0.f};
                        f16x8 b0 = *(const f16x8*)&U_all[frow][co + fk];
                        f16x8 b1 = *(const f16x8*)&U_all[frow][co + fk + 32];
                        acc = __builtin_amdgcn_mfma_f32_16x16x32_f16(aT[0], b0, acc, 0, 0, 0);
                        acc = __builtin_amdgcn_mfma_f32_16x16x32_f16(aT[1], b1, acc, 0, 0, 0);
#pragma unroll
                        for (int ks = 0; ks < 4; ++ks) {
                            f16x8 sv = *(const f16x8*)&S_buf[pb][j][frow][fk + 32 * ks];
                            acc = __builtin_amdgcn_mfma_f32_16x16x32_f16(aG[ks], sv, acc, 0, 0, 0);
                        }
                        f16x4 uf = *(const f16x4*)&U_all[frow][co + t0];
                        f32x4 yv;
#pragma unroll
                        for (int k = 0; k < 4; ++k) yv[k] = acc[k] + Dv * (float)uf[k];
                        if (layer == N_LAYERS - 1) {
                            f16x4 o;
#pragma unroll
                            for (int k = 0; k < 4; ++k) o[k] = (f16)yv[k];
                            *(f16x4*)&yb[(size_t)frow * L_SEQ + co + t0] = o;
                        } else {
                            if (jj == 0) yh0 = yv; else yh1 = yv;
                        }
                    }
                }
            }
            barrier_lgkm();
        }

        // ---- final states from scan registers ----
        if (zrole) {
            const int na = wave * 8 + fq * 2;
            const size_t base = (((size_t)layer * B_SZ + frow) * H_SZ + h) * N_ST + na;
            st_re[base]     = s0r; st_im[base]     = s0i;
            st_re[base + 1] = s1r; st_im[base + 1] = s1i;
        }
        __syncthreads();   // tables / U_all safe to overwrite for next layer
    }
}

// ---------- [H][B][L] f16 -> [L][B][H] f32 transpose ----------
__global__ __launch_bounds__(256, 4)
void hbl_to_lbh_kernel(const f16* __restrict__ in, float* __restrict__ out)
{
    __shared__ float t_sh[64][65];
    const int tid = threadIdx.x, bid = blockIdx.x;
    const int bb = bid & 15, lt = (bid >> 4) & 31, ht = bid >> 9;
    const int l0 = lt * 64, h0 = ht * 64;
#pragma unroll
    for (int i = 0; i < 4; ++i) {
        int idx = tid + i * 256;
        int hh = idx >> 4, l4 = (idx & 15) * 4;
        f16x4 v = *(const f16x4*)&in[((size_t)(h0 + hh) * B_SZ + bb) * L_SEQ + l0 + l4];
#pragma unroll
        for (int k = 0; k < 4; ++k) t_sh[hh][l4 + k] = (float)v[k];
    }
    __syncthreads();
#pragma unroll
    for (int i = 0; i < 16; ++i) {
        int idx = tid + i * 256;
        int ll = idx >> 6, hh = idx & 63;
        out[((size_t)(l0 + ll) * B_SZ + bb) * H_SZ + h0 + hh] = t_sh[hh][ll];
    }
}

extern "C" void kernel_launch(void* const* d_in, const int* in_sizes, int n_in,
                              void* d_out, int out_size, void* d_ws, size_t ws_size,
                              hipStream_t stream)
{
    const float* x        = (const float*)d_in[0];
    const float* enc_W    = (const float*)d_in[1];
    const float* enc_b    = (const float*)d_in[2];
    const float* log_dt   = (const float*)d_in[3];
    const float* log_A_re = (const float*)d_in[4];
    const float* A_im     = (const float*)d_in[5];
    const float* C_re     = (const float*)d_in[6];
    const float* C_im     = (const float*)d_in[7];
    const float* Dskip    = (const float*)d_in[8];

    float* out_lbh = (float*)d_out;                                  // [L,B,H]
    float* st_re   = out_lbh + (size_t)L_SEQ * B_SZ * H_SZ;
    float* st_im   = st_re + (size_t)N_LAYERS * B_SZ * H_SZ * N_ST;
    f16*   B0      = (f16*)d_ws;     // [H][B][L] f16 activations (32 MB)

    encoder_mfma_kernel<<<4096, 256, 0, stream>>>(x, enc_W, enc_b, B0);

    s4d_fused_kernel<<<512, 1024, 0, stream>>>(B0, log_dt, log_A_re, A_im,
                                               C_re, C_im, Dskip, st_re, st_im);

    hbl_to_lbh_kernel<<<4096, 256, 0, stream>>>(B0, out_lbh);        // final y -> [L,B,H]
}

// Round 4
// 243.294 us; speedup vs baseline: 1.4736x; 1.0820x over previous
//
#include <hip/hip_runtime.h>
#include <math.h>

#define L_SEQ 2048
#define B_SZ 16
#define DIN 64
#define H_SZ 512
#define N_ST 64
#define N_LAYERS 4
#define Q_CHUNK 64
#define N_CHUNKS (L_SEQ / Q_CHUNK)   // 32
#define GSZ 4                         // chunks per pipeline group
#define N_GROUPS (N_CHUNKS / GSZ)     // 8
#define UPAD 2056                     // U_all row stride in f16 (16B-aligned)
#define NTHR 768                      // 12 waves

typedef _Float16 f16;
typedef _Float16 f16x8 __attribute__((ext_vector_type(8)));
typedef _Float16 f16x4 __attribute__((ext_vector_type(4)));
typedef float    f32x4 __attribute__((ext_vector_type(4)));

struct cx { float r, i; };
__device__ __forceinline__ cx cmul(cx a, cx b) {
    return { a.r * b.r - a.i * b.i, a.r * b.i + a.i * b.r };
}

// LDS-only barrier (global loads/stores may stay in flight across it)
__device__ __forceinline__ void barrier_lgkm() {
    asm volatile("s_waitcnt lgkmcnt(0)\n\ts_barrier" ::: "memory");
}

// ---------- encoder (MFMA): out[h][b][l] = f16( sum_k x[l][b][k] W[k][h] + bias[h] ) ----------
__global__ __launch_bounds__(256, 4)
void encoder_mfma_kernel(const float* __restrict__ x, const float* __restrict__ W,
                         const float* __restrict__ bias, f16* __restrict__ out)
{
    __shared__ f16   x_sh[64][72];    // [l][k]
    __shared__ f16   w_t[64][72];     // [h][k]
    __shared__ float out_sh[64][68];
    __shared__ float b_sh[64];
    const int tid = threadIdx.x;
    const int bid = blockIdx.x;
    const int bb  = bid & 15;
    const int lt  = (bid >> 4) & 31;
    const int ht  = bid >> 9;
    const int l0 = lt * 64, h0 = ht * 64;

#pragma unroll
    for (int i = 0; i < 16; ++i) {
        int idx = tid + i * 256;
        int r = idx >> 6, c = idx & 63;
        x_sh[r][c] = (f16)x[((size_t)(l0 + r) * B_SZ + bb) * DIN + c];  // r=l, c=k
        w_t[c][r]  = (f16)W[(size_t)r * H_SZ + h0 + c];                 // r=k, c=h
    }
    if (tid < 64) b_sh[tid] = bias[h0 + tid];
    __syncthreads();

    const int wave = tid >> 6;
    const int lane = tid & 63;
    const int frow = lane & 15;
    const int fk   = (lane >> 4) * 8;
    const int m0   = wave * 16;            // h strip per wave

    f16x8 a0 = *(const f16x8*)&w_t[m0 + frow][fk];
    f16x8 a1 = *(const f16x8*)&w_t[m0 + frow][fk + 32];
    float bv[4];
#pragma unroll
    for (int j = 0; j < 4; ++j) bv[j] = b_sh[m0 + (lane >> 4) * 4 + j];

#pragma unroll
    for (int nt = 0; nt < 4; ++nt) {       // l tiles
        f16x8 b0 = *(const f16x8*)&x_sh[nt * 16 + frow][fk];
        f16x8 b1 = *(const f16x8*)&x_sh[nt * 16 + frow][fk + 32];
        f32x4 acc = {0.f, 0.f, 0.f, 0.f};
        acc = __builtin_amdgcn_mfma_f32_16x16x32_f16(a0, b0, acc, 0, 0, 0);
        acc = __builtin_amdgcn_mfma_f32_16x16x32_f16(a1, b1, acc, 0, 0, 0);
#pragma unroll
        for (int j = 0; j < 4; ++j)
            out_sh[m0 + (lane >> 4) * 4 + j][nt * 16 + frow] = acc[j] + bv[j];
    }
    __syncthreads();

#pragma unroll
    for (int i = 0; i < 4; ++i) {
        int row = (tid >> 4) + i * 16;     // h row
        int c4  = (tid & 15) * 4;          // l col
        f32x4 v = *(const f32x4*)&out_sh[row][c4];
        f16x4 o;
#pragma unroll
        for (int k = 0; k < 4; ++k) o[k] = (f16)v[k];
        *(f16x4*)&out[((size_t)(h0 + row) * B_SZ + bb) * L_SEQ + l0 + c4] = o;
    }
}

// ---------- fused 4-layer S4D: one block per h, sequence LDS-resident ----------
// 12 waves (768 thr). Wave roles in the group-pipelined main loop:
//   waves 0-3 ("scan"): wave w owns n in [16w,16w+16): publish S_pre -> S_buf;
//                       Z_re = E_re.U (2 MFMA) + Z_im = E_im.U (2 MFMA);
//                       register scan of 4 complex pairs per lane.
//   waves 4-11 ("out"): wave = (chunk jc=ow>>1, m-half mh=ow&1, 32 rows):
//                       y = T.U + G.S + D*u (12 MFMA), group lag 1;
//                       in-place writeback to U_all at lag 2 (layers 0-2),
//                       global f16 store at layer 3.
// E stored as separate Re rows (64..127) and Im rows (128..191) so each scan
// wave loads matched Re/Im tiles (acc pairs stay lane-local for the scan).
// G_lds holds G_ext[j] = (2Re(C dA^j), -2Im(C dA^j)) for j=0..64; main loop
// uses rows 1.., the K-vector dot uses rows 0..63 (K[d] = G_ext[d].dBv).
__global__ __launch_bounds__(NTHR, 3)
void s4d_fused_kernel(f16* __restrict__ u_io,          // [H][B][L] f16: encoder out; final y in place
                      const float* __restrict__ log_dt, const float* __restrict__ log_A_re,
                      const float* __restrict__ A_im, const float* __restrict__ C_re,
                      const float* __restrict__ C_im, const float* __restrict__ Dskip,
                      float* __restrict__ st_re, float* __restrict__ st_im)
{
    __shared__ f16   A_lds[192][72];         // 0-63: Toeplitz(K); 64-127: E_re[n][m]; 128-191: E_im[n][m]
    __shared__ f16   G_lds[65][136];         // G_ext[j][n2], j=0..64
    __shared__ f16   U_all[16][UPAD];        // whole per-h sequence, f16, in place across layers
    __shared__ f16   S_buf[2][GSZ][16][136]; // S_pre per chunk of group [b][n2]
    __shared__ float dBv_sh[128];            // (dBr,dBi) interleaved per n
    __shared__ float K_sh[64];
    __shared__ float w_sh[64][2];            // dA^64 per n
    // total: 27648+17680+65792+34816+512+256+512 = 147216 B -> 1 block/CU

    const int tid  = threadIdx.x;
    const int wave = tid >> 6;
    const int lane = tid & 63;
    const int h    = blockIdx.x;
    const int frow = lane & 15;
    const int fq   = lane >> 4;
    const int fk   = fq * 8;

    // ---- stage the whole layer-0 input sequence into LDS ----
    {
        const f16* ub = u_io + (size_t)h * B_SZ * L_SEQ;
        for (int u0 = tid; u0 < 16 * 256; u0 += NTHR) {
            int b = u0 >> 8, cidx = (u0 & 255) * 8;
            *(f16x8*)&U_all[b][cidx] = *(const f16x8*)&ub[(size_t)b * L_SEQ + cidx];
        }
    }
    f16* yb = u_io + (size_t)h * B_SZ * L_SEQ;   // final-layer f16 output (same h slot, safe)

    for (int layer = 0; layer < N_LAYERS; ++layer) {
        const int ph = layer * H_SZ + h;
        const int pn = ph * N_ST + lane;

        // ---- table build: 12 waves = 4 roles x 3 power segments ----
        {
            float dt   = expf(log_dt[ph]);
            float Are  = -expf(log_A_re[pn]);
            float Aim  = A_im[pn];
            float mg   = expf(dt * Are);
            float phs  = dt * Aim;
            cx dA1 = { mg * cosf(phs), mg * sinf(phs) };
            float invd = 1.0f / (Are * Are + Aim * Aim);
            float nr   = dA1.r - 1.0f;
            float dBr  = (nr * Are + dA1.i * Aim) * invd;
            float dBi  = (dA1.i * Are - nr * Aim) * invd;
            float Cr   = C_re[pn];
            float Ci   = C_im[pn];
            if (wave == 0) { dBv_sh[2 * lane] = dBr; dBv_sh[2 * lane + 1] = dBi; }

            const int role = wave & 3;     // 0:E_re 1:E_im 2:G_even 3:G_odd(+w)
            const int seg  = wave >> 2;    // 0,1,2
            cx dA2  = cmul(dA1, dA1);
            cx dA4  = cmul(dA2, dA2);
            cx dA8  = cmul(dA4, dA4);
            cx dA16 = cmul(dA8, dA8);
            cx P = { 1.f, 0.f };
            int j0 = 0, jend = 21;
            if (seg >= 1) { P = cmul(cmul(dA16, dA4), dA1); j0 = 21; jend = 42; }   // dA^21
            if (seg == 2) { P = cmul(P, P); j0 = 42; jend = (role >= 2) ? 65 : 64; } // dA^42
            for (int j = j0; j < jend; ++j) {
                if (role == 0)      A_lds[64  + lane][63 - j] = (f16)(P.r * dBr - P.i * dBi);
                else if (role == 1) A_lds[128 + lane][63 - j] = (f16)(P.r * dBi + P.i * dBr);
                else if (role == 2) G_lds[j][2 * lane]     = (f16)( 2.f * (Cr * P.r - Ci * P.i));
                else {
                    G_lds[j][2 * lane + 1] = (f16)(-2.f * (Cr * P.i + Ci * P.r));
                    if (j == 64) { w_sh[lane][0] = P.r; w_sh[lane][1] = P.i; }
                }
                P = cmul(P, dA1);
            }
        }
        barrier_lgkm();

        // ---- K[d] = G_ext[d] . dBv  (all 64 d in parallel, 8 lanes per d) ----
        if (tid < 512) {
            const int t  = tid >> 3;
            const int l8 = tid & 7;
            f16x8 g0 = *(const f16x8*)&G_lds[t][l8 * 16];
            f16x8 g1 = *(const f16x8*)&G_lds[t][l8 * 16 + 8];
            f32x4 d0 = *(const f32x4*)&dBv_sh[l8 * 16];
            f32x4 d1 = *(const f32x4*)&dBv_sh[l8 * 16 + 4];
            f32x4 d2 = *(const f32x4*)&dBv_sh[l8 * 16 + 8];
            f32x4 d3 = *(const f32x4*)&dBv_sh[l8 * 16 + 12];
            float acc = 0.f;
#pragma unroll
            for (int k = 0; k < 4; ++k) {
                acc += (float)g0[k]     * d0[k];
                acc += (float)g0[k + 4] * d1[k];
                acc += (float)g1[k]     * d2[k];
                acc += (float)g1[k + 4] * d3[k];
            }
            acc += __shfl_xor(acc, 1);
            acc += __shfl_xor(acc, 2);
            acc += __shfl_xor(acc, 4);
            if (l8 == 0) K_sh[t] = acc;
        }
        barrier_lgkm();
        for (int e = tid; e < 64 * 64; e += NTHR) {   // Toeplitz expansion
            int i = e >> 6, jc = e & 63;
            A_lds[i][jc] = (jc <= i) ? (f16)K_sh[i - jc] : (f16)0.f;
        }
        barrier_lgkm();

        // ---- per-role chunk-invariant fragments / constants ----
        const float Dv = Dskip[ph];
        f16x8 aRe0, aRe1, aIm0, aIm1;            // scan
        f16x8 aT0[2], aT1[2], aG[2][4];          // out
        float wr4[4], wi4[4];
        float s_r[4] = {0.f,0.f,0.f,0.f}, s_i[4] = {0.f,0.f,0.f,0.f};
        if (wave < 4) {
            const int m0 = 16 * wave;
            aRe0 = *(const f16x8*)&A_lds[64  + m0 + frow][fk];
            aRe1 = *(const f16x8*)&A_lds[64  + m0 + frow][fk + 32];
            aIm0 = *(const f16x8*)&A_lds[128 + m0 + frow][fk];
            aIm1 = *(const f16x8*)&A_lds[128 + m0 + frow][fk + 32];
#pragma unroll
            for (int p = 0; p < 4; ++p) {
                int n = m0 + fq * 4 + p;
                wr4[p] = w_sh[n][0]; wi4[p] = w_sh[n][1];
            }
        } else {
            const int mh = (wave - 4) & 1;
#pragma unroll
            for (int mt = 0; mt < 2; ++mt) {
                const int r0 = 32 * mh + 16 * mt + frow;
                aT0[mt] = *(const f16x8*)&A_lds[r0][fk];
                aT1[mt] = *(const f16x8*)&A_lds[r0][fk + 32];
#pragma unroll
                for (int k4 = 0; k4 < 4; ++k4)
                    aG[mt][k4] = *(const f16x8*)&G_lds[1 + r0][fk + 32 * k4];
            }
        }
        f16x4 yh[2];   // held y (layers 0-2), set at g>=1 before first use at g>=2

        // ---- main pipelined group loop: ONE barrier per group-iteration ----
        for (int g = 0; g <= N_GROUPS + 1; ++g) {
            if (wave < 4) {
                if (g < N_GROUPS) {
                    const int gb = g & 1;
#pragma unroll
                    for (int j = 0; j < GSZ; ++j) {
                        f16x8 sf;
                        sf[0] = (f16)s_r[0]; sf[1] = (f16)s_i[0];
                        sf[2] = (f16)s_r[1]; sf[3] = (f16)s_i[1];
                        sf[4] = (f16)s_r[2]; sf[5] = (f16)s_i[2];
                        sf[6] = (f16)s_r[3]; sf[7] = (f16)s_i[3];
                        *(f16x8*)&S_buf[gb][j][frow][32 * wave + 8 * fq] = sf;
                        const int co = (g * GSZ + j) * 64;
                        f16x8 b0 = *(const f16x8*)&U_all[frow][co + fk];
                        f16x8 b1 = *(const f16x8*)&U_all[frow][co + fk + 32];
                        f32x4 aR = {0.f,0.f,0.f,0.f}, aI = {0.f,0.f,0.f,0.f};
                        aR = __builtin_amdgcn_mfma_f32_16x16x32_f16(aRe0, b0, aR, 0, 0, 0);
                        aR = __builtin_amdgcn_mfma_f32_16x16x32_f16(aRe1, b1, aR, 0, 0, 0);
                        aI = __builtin_amdgcn_mfma_f32_16x16x32_f16(aIm0, b0, aI, 0, 0, 0);
                        aI = __builtin_amdgcn_mfma_f32_16x16x32_f16(aIm1, b1, aI, 0, 0, 0);
#pragma unroll
                        for (int p = 0; p < 4; ++p) {
                            float nr2 = wr4[p] * s_r[p] - wi4[p] * s_i[p] + aR[p];
                            float ni2 = wi4[p] * s_r[p] + wr4[p] * s_i[p] + aI[p];
                            s_r[p] = nr2; s_i[p] = ni2;
                        }
                    }
                }
            } else {
                const int ow = wave - 4, jc = ow >> 1, mh = ow & 1;
                if (layer < N_LAYERS - 1 && g >= 2) {    // writeback group g-2
                    const int co2 = ((g - 2) * GSZ + jc) * 64;
                    *(f16x4*)&U_all[frow][co2 + 32 * mh + fq * 4]      = yh[0];
                    *(f16x4*)&U_all[frow][co2 + 32 * mh + 16 + fq * 4] = yh[1];
                }
                if (g >= 1 && g <= N_GROUPS) {           // compute group g-1
                    const int gp = g - 1, pb = gp & 1;
                    const int co = (gp * GSZ + jc) * 64;
                    f16x8 b0 = *(const f16x8*)&U_all[frow][co + fk];
                    f16x8 b1 = *(const f16x8*)&U_all[frow][co + fk + 32];
                    f16x8 sv0 = *(const f16x8*)&S_buf[pb][jc][frow][fk];
                    f16x8 sv1 = *(const f16x8*)&S_buf[pb][jc][frow][fk + 32];
                    f16x8 sv2 = *(const f16x8*)&S_buf[pb][jc][frow][fk + 64];
                    f16x8 sv3 = *(const f16x8*)&S_buf[pb][jc][frow][fk + 96];
#pragma unroll
                    for (int mt = 0; mt < 2; ++mt) {
                        f32x4 acc = {0.f,0.f,0.f,0.f};
                        acc = __builtin_amdgcn_mfma_f32_16x16x32_f16(aT0[mt], b0, acc, 0, 0, 0);
                        acc = __builtin_amdgcn_mfma_f32_16x16x32_f16(aT1[mt], b1, acc, 0, 0, 0);
                        acc = __builtin_amdgcn_mfma_f32_16x16x32_f16(aG[mt][0], sv0, acc, 0, 0, 0);
                        acc = __builtin_amdgcn_mfma_f32_16x16x32_f16(aG[mt][1], sv1, acc, 0, 0, 0);
                        acc = __builtin_amdgcn_mfma_f32_16x16x32_f16(aG[mt][2], sv2, acc, 0, 0, 0);
                        acc = __builtin_amdgcn_mfma_f32_16x16x32_f16(aG[mt][3], sv3, acc, 0, 0, 0);
                        const int t0 = 32 * mh + 16 * mt + fq * 4;
                        f16x4 uf = *(const f16x4*)&U_all[frow][co + t0];
                        f16x4 o;
#pragma unroll
                        for (int k = 0; k < 4; ++k) o[k] = (f16)(acc[k] + Dv * (float)uf[k]);
                        if (layer == N_LAYERS - 1)
                            *(f16x4*)&yb[(size_t)frow * L_SEQ + co + t0] = o;
                        else
                            yh[mt] = o;
                    }
                }
            }
            barrier_lgkm();
        }

        // ---- final states from scan registers ----
        if (wave < 4) {
#pragma unroll
            for (int p = 0; p < 4; ++p) {
                int n = 16 * wave + 4 * fq + p;
                size_t base = (((size_t)layer * B_SZ + frow) * H_SZ + h) * N_ST + n;
                st_re[base] = s_r[p];
                st_im[base] = s_i[p];
            }
        }
        __syncthreads();   // tables / U_all safe to overwrite for next layer
    }
}

// ---------- [H][B][L] f16 -> [L][B][H] f32 transpose ----------
__global__ __launch_bounds__(256, 4)
void hbl_to_lbh_kernel(const f16* __restrict__ in, float* __restrict__ out)
{
    __shared__ float t_sh[64][65];
    const int tid = threadIdx.x, bid = blockIdx.x;
    const int bb = bid & 15, lt = (bid >> 4) & 31, ht = bid >> 9;
    const int l0 = lt * 64, h0 = ht * 64;
#pragma unroll
    for (int i = 0; i < 4; ++i) {
        int idx = tid + i * 256;
        int hh = idx >> 4, l4 = (idx & 15) * 4;
        f16x4 v = *(const f16x4*)&in[((size_t)(h0 + hh) * B_SZ + bb) * L_SEQ + l0 + l4];
#pragma unroll
        for (int k = 0; k < 4; ++k) t_sh[hh][l4 + k] = (float)v[k];
    }
    __syncthreads();
#pragma unroll
    for (int i = 0; i < 16; ++i) {
        int idx = tid + i * 256;
        int ll = idx >> 6, hh = idx & 63;
        out[((size_t)(l0 + ll) * B_SZ + bb) * H_SZ + h0 + hh] = t_sh[hh][ll];
    }
}

extern "C" void kernel_launch(void* const* d_in, const int* in_sizes, int n_in,
                              void* d_out, int out_size, void* d_ws, size_t ws_size,
                              hipStream_t stream)
{
    const float* x        = (const float*)d_in[0];
    const float* enc_W    = (const float*)d_in[1];
    const float* enc_b    = (const float*)d_in[2];
    const float* log_dt   = (const float*)d_in[3];
    const float* log_A_re = (const float*)d_in[4];
    const float* A_im     = (const float*)d_in[5];
    const float* C_re     = (const float*)d_in[6];
    const float* C_im     = (const float*)d_in[7];
    const float* Dskip    = (const float*)d_in[8];

    float* out_lbh = (float*)d_out;                                  // [L,B,H]
    float* st_re   = out_lbh + (size_t)L_SEQ * B_SZ * H_SZ;
    float* st_im   = st_re + (size_t)N_LAYERS * B_SZ * H_SZ * N_ST;
    f16*   B0      = (f16*)d_ws;     // [H][B][L] f16 activations (32 MB)

    encoder_mfma_kernel<<<4096, 256, 0, stream>>>(x, enc_W, enc_b, B0);

    s4d_fused_kernel<<<512, NTHR, 0, stream>>>(B0, log_dt, log_A_re, A_im,
                                               C_re, C_im, Dskip, st_re, st_im);

    hbl_to_lbh_kernel<<<4096, 256, 0, stream>>>(B0, out_lbh);        // final y -> [L,B,H]
}